// Round 1
// baseline (197.327 us; speedup 1.0000x reference)
//
#include <hip/hip_runtime.h>
#include <hip/hip_bf16.h>

typedef __attribute__((ext_vector_type(8))) short bf16x8;
typedef __attribute__((ext_vector_type(4))) float f32x4;

#define DIM 512
#define NH 8
#define HD 64
#define SEQ 1024
#define NB 8
#define ROWS (NB*SEQ)

__device__ __forceinline__ short f2bf(float f) {
  union { float f; unsigned u; } v; v.f = f;
  unsigned r = v.u + 0x7fffu + ((v.u >> 16) & 1u);
  return (short)(r >> 16);
}

__device__ __forceinline__ f32x4 mfma16(bf16x8 a, bf16x8 b, f32x4 c) {
  return __builtin_amdgcn_mfma_f32_16x16x32_bf16(a, b, c, 0, 0, 0);
}

// ---------------- LayerNorm: x[8192][512] -> xn fp32 + bf16 ----------------
__global__ __launch_bounds__(256) void ln_kernel(const float* __restrict__ x,
    const float* __restrict__ gamma, const float* __restrict__ beta,
    float* __restrict__ xnf, short* __restrict__ xnb) {
  const int row = blockIdx.x;
  const int t = threadIdx.x;
  const float2 v = reinterpret_cast<const float2*>(x + (size_t)row * DIM)[t];
  float s = v.x + v.y;
  float sq = v.x * v.x + v.y * v.y;
  for (int off = 1; off < 64; off <<= 1) {
    s += __shfl_xor(s, off);
    sq += __shfl_xor(sq, off);
  }
  __shared__ float sred[8];
  const int w = t >> 6, lane = t & 63;
  if (lane == 0) { sred[w] = s; sred[4 + w] = sq; }
  __syncthreads();
  s = sred[0] + sred[1] + sred[2] + sred[3];
  sq = sred[4] + sred[5] + sred[6] + sred[7];
  const float mean = s * (1.0f / DIM);
  const float var = sq * (1.0f / DIM) - mean * mean;
  const float rs = rsqrtf(var + 1e-5f);
  const float2 g = reinterpret_cast<const float2*>(gamma)[t];
  const float2 bb = reinterpret_cast<const float2*>(beta)[t];
  const float y0 = (v.x - mean) * rs * g.x + bb.x;
  const float y1 = (v.y - mean) * rs * g.y + bb.y;
  reinterpret_cast<float2*>(xnf + (size_t)row * DIM)[t] = make_float2(y0, y1);
  short2 o; o.x = f2bf(y0); o.y = f2bf(y1);
  reinterpret_cast<short2*>(xnb + (size_t)row * DIM)[t] = o;
}

// ------------- weights: W[k][n] fp32 -> WT[n][k] bf16 (4 at once) -------------
__global__ __launch_bounds__(256) void wtrans_kernel(
    const float* __restrict__ W0, const float* __restrict__ W1,
    const float* __restrict__ W2, const float* __restrict__ W3,
    short* __restrict__ D0, short* __restrict__ D1,
    short* __restrict__ D2, short* __restrict__ D3) {
  const float* W; short* D;
  switch (blockIdx.y) {
    case 0: W = W0; D = D0; break;
    case 1: W = W1; D = D1; break;
    case 2: W = W2; D = D2; break;
    default: W = W3; D = D3; break;
  }
  const int idx = blockIdx.x * 256 + threadIdx.x;
  const int n = idx >> 9, k = idx & 511;
  D[idx] = f2bf(W[(size_t)k * 512 + n]);
}

// ---------------- QKV GEMM: xn_bf16 @ W{q,k,v}T -> Q,K bf16 rowmajor; V -> Vt[inst][64][1024]
__global__ __launch_bounds__(256) void gemm_qkv(const short* __restrict__ A,
    const short* __restrict__ WqT, const short* __restrict__ WkT,
    const short* __restrict__ WvT, short* __restrict__ Qo,
    short* __restrict__ Ko, short* __restrict__ VtO) {
  const int z = blockIdx.z;
  const short* BT = (z == 0) ? WqT : (z == 1) ? WkT : WvT;
  const int m0 = blockIdx.x * 64, n0 = blockIdx.y * 64;
  const int t = threadIdx.x, w = t >> 6, lane = t & 63, g = lane >> 4, c16 = lane & 15;
  const int wr = w >> 1, wc = w & 1;
  __shared__ short As[64 * 40];
  __shared__ short Bs[64 * 40];
  f32x4 acc[2][2] = {};
  const int srow = t >> 2, sseg = t & 3;
  for (int kb = 0; kb < 512; kb += 32) {
    __syncthreads();
    *reinterpret_cast<bf16x8*>(&As[srow * 40 + 8 * sseg]) =
        *reinterpret_cast<const bf16x8*>(&A[(size_t)(m0 + srow) * 512 + kb + 8 * sseg]);
    *reinterpret_cast<bf16x8*>(&Bs[srow * 40 + 8 * sseg]) =
        *reinterpret_cast<const bf16x8*>(&BT[(size_t)(n0 + srow) * 512 + kb + 8 * sseg]);
    __syncthreads();
    bf16x8 a0 = *reinterpret_cast<const bf16x8*>(&As[(32 * wr + c16) * 40 + 8 * g]);
    bf16x8 a1 = *reinterpret_cast<const bf16x8*>(&As[(32 * wr + 16 + c16) * 40 + 8 * g]);
    bf16x8 b0 = *reinterpret_cast<const bf16x8*>(&Bs[(32 * wc + c16) * 40 + 8 * g]);
    bf16x8 b1 = *reinterpret_cast<const bf16x8*>(&Bs[(32 * wc + 16 + c16) * 40 + 8 * g]);
    acc[0][0] = mfma16(a0, b0, acc[0][0]);
    acc[0][1] = mfma16(a0, b1, acc[0][1]);
    acc[1][0] = mfma16(a1, b0, acc[1][0]);
    acc[1][1] = mfma16(a1, b1, acc[1][1]);
  }
#pragma unroll
  for (int i = 0; i < 2; ++i)
#pragma unroll
    for (int j = 0; j < 2; ++j)
#pragma unroll
      for (int e = 0; e < 4; ++e) {
        const int row = m0 + 32 * wr + 16 * i + 4 * g + e;
        const int col = n0 + 32 * wc + 16 * j + c16;
        const short v = f2bf(acc[i][j][e]);
        if (z == 0) {
          Qo[(size_t)row * 512 + col] = v;
        } else if (z == 1) {
          Ko[(size_t)row * 512 + col] = v;
        } else {
          const int bb = row >> 10, ss = row & 1023, hh = col >> 6, dd = col & 63;
          VtO[((size_t)(bb * NH + hh)) * 65536 + dd * 1024 + ss] = v;
        }
      }
}

// ---------------- fused scores + softmax + attn write + PV ----------------
// grid (64 rowblocks, 8 heads, 8 batches), 256 thr. 16 Q-rows per block.
__global__ __launch_bounds__(256) void attn_kernel(
    const short* __restrict__ Qb, const short* __restrict__ Kb,
    const short* __restrict__ Vt, float* __restrict__ attnOut,
    short* __restrict__ Lg) {
  const int rb = blockIdx.x, h = blockIdx.y, b = blockIdx.z;
  const int inst = b * NH + h;
  const int t = threadIdx.x;
  const int w = t >> 6, lane = t & 63, g = lane >> 4, c16 = lane & 15;

  __shared__ short Klds[128 * 72];   // 128 K-rows x 64 d, padded to 72
  __shared__ short Plds[16 * 1032];  // 16 rows x 1024 cols, padded
  __shared__ float red[2][4][16];

  bf16x8 qf0, qf1;
  {
    const short* qp = Qb + ((size_t)(b * SEQ + rb * 16 + c16)) * DIM + h * HD + 8 * g;
    qf0 = *reinterpret_cast<const bf16x8*>(qp);
    qf1 = *reinterpret_cast<const bf16x8*>(qp + 32);
  }

  f32x4 acc[16] = {};

  for (int c = 0; c < 8; ++c) {
    __syncthreads();
#pragma unroll
    for (int p = 0; p < 4; ++p) {
      const int r = p * 32 + (t >> 3), seg = t & 7;
      *reinterpret_cast<bf16x8*>(&Klds[r * 72 + 8 * seg]) =
          *reinterpret_cast<const bf16x8*>(
              &Kb[((size_t)(b * SEQ + c * 128 + r)) * DIM + h * HD + 8 * seg]);
    }
    __syncthreads();
#pragma unroll
    for (int j = 0; j < 2; ++j) {
      const int lr = 16 * (2 * w + j) + c16;
      bf16x8 k0 = *reinterpret_cast<const bf16x8*>(&Klds[lr * 72 + 8 * g]);
      bf16x8 k1 = *reinterpret_cast<const bf16x8*>(&Klds[lr * 72 + 32 + 8 * g]);
      const int tt = c * 2 + j;
      acc[tt] = mfma16(qf0, k0, acc[tt]);
      acc[tt] = mfma16(qf1, k1, acc[tt]);
    }
  }

  // scale by 1/sqrt(64)
#pragma unroll
  for (int tt = 0; tt < 16; ++tt)
#pragma unroll
    for (int i = 0; i < 4; ++i) acc[tt][i] *= 0.125f;

  // row max (rows = 4*g + i), reduce over 16 lanes of group then across waves
  float m[4];
#pragma unroll
  for (int i = 0; i < 4; ++i) m[i] = -1e30f;
#pragma unroll
  for (int tt = 0; tt < 16; ++tt)
#pragma unroll
    for (int i = 0; i < 4; ++i) m[i] = fmaxf(m[i], acc[tt][i]);
  for (int off = 1; off < 16; off <<= 1)
#pragma unroll
    for (int i = 0; i < 4; ++i) m[i] = fmaxf(m[i], __shfl_xor(m[i], off));
  if (c16 == 0) {
#pragma unroll
    for (int i = 0; i < 4; ++i) red[0][w][4 * g + i] = m[i];
  }
  __syncthreads();
#pragma unroll
  for (int i = 0; i < 4; ++i) {
    float mm = red[0][0][4 * g + i];
    mm = fmaxf(mm, red[0][1][4 * g + i]);
    mm = fmaxf(mm, red[0][2][4 * g + i]);
    mm = fmaxf(mm, red[0][3][4 * g + i]);
    m[i] = mm;
  }

  float sm[4] = {0.f, 0.f, 0.f, 0.f};
#pragma unroll
  for (int tt = 0; tt < 16; ++tt)
#pragma unroll
    for (int i = 0; i < 4; ++i) {
      const float p = __expf(acc[tt][i] - m[i]);
      acc[tt][i] = p;
      sm[i] += p;
    }
  for (int off = 1; off < 16; off <<= 1)
#pragma unroll
    for (int i = 0; i < 4; ++i) sm[i] += __shfl_xor(sm[i], off);
  if (c16 == 0) {
#pragma unroll
    for (int i = 0; i < 4; ++i) red[1][w][4 * g + i] = sm[i];
  }
  __syncthreads();
  float rinv[4];
#pragma unroll
  for (int i = 0; i < 4; ++i) {
    const float ss = red[1][0][4 * g + i] + red[1][1][4 * g + i] +
                     red[1][2][4 * g + i] + red[1][3][4 * g + i];
    rinv[i] = 1.0f / ss;
  }

  // write normalized attn (fp32 output) + stage P bf16 to LDS
  const size_t abase = (size_t)b * 8388608 + (size_t)h * 1024;
#pragma unroll
  for (int c = 0; c < 8; ++c)
#pragma unroll
    for (int j = 0; j < 2; ++j) {
      const int col = 16 * (8 * c + 2 * w + j) + c16;
      const int tt = c * 2 + j;
#pragma unroll
      for (int i = 0; i < 4; ++i) {
        const int row = 4 * g + i;
        const float pv = acc[tt][i] * rinv[i];
        attnOut[abase + (size_t)(rb * 16 + row) * 8192 + col] = pv;
        Plds[row * 1032 + col] = f2bf(pv);
      }
    }
  __syncthreads();

  // PV: logits[16 x 64] = P[16 x 1024] @ V[1024 x 64]; wave w -> d cols [16w,16w+16)
  f32x4 pacc = {};
  const short* vbase = Vt + (size_t)inst * 65536 + (16 * w + c16) * 1024 + 8 * g;
#pragma unroll
  for (int kk = 0; kk < 32; ++kk) {
    bf16x8 pa = *reinterpret_cast<const bf16x8*>(&Plds[c16 * 1032 + 32 * kk + 8 * g]);
    bf16x8 vb = *reinterpret_cast<const bf16x8*>(vbase + 32 * kk);
    pacc = mfma16(pa, vb, pacc);
  }
#pragma unroll
  for (int e = 0; e < 4; ++e) {
    Lg[((size_t)(b * SEQ + rb * 16 + 4 * g + e)) * DIM + h * HD + 16 * w + c16] =
        f2bf(pacc[e]);
  }
}

// ---------------- out = logits @ Wo + xn (fp32) ----------------
__global__ __launch_bounds__(256) void gemm_out(const short* __restrict__ A,
    const short* __restrict__ BT, const float* __restrict__ xnf,
    float* __restrict__ out) {
  const int m0 = blockIdx.x * 64, n0 = blockIdx.y * 64;
  const int t = threadIdx.x, w = t >> 6, lane = t & 63, g = lane >> 4, c16 = lane & 15;
  const int wr = w >> 1, wc = w & 1;
  __shared__ short As[64 * 40];
  __shared__ short Bs[64 * 40];
  f32x4 acc[2][2] = {};
  const int srow = t >> 2, sseg = t & 3;
  for (int kb = 0; kb < 512; kb += 32) {
    __syncthreads();
    *reinterpret_cast<bf16x8*>(&As[srow * 40 + 8 * sseg]) =
        *reinterpret_cast<const bf16x8*>(&A[(size_t)(m0 + srow) * 512 + kb + 8 * sseg]);
    *reinterpret_cast<bf16x8*>(&Bs[srow * 40 + 8 * sseg]) =
        *reinterpret_cast<const bf16x8*>(&BT[(size_t)(n0 + srow) * 512 + kb + 8 * sseg]);
    __syncthreads();
    bf16x8 a0 = *reinterpret_cast<const bf16x8*>(&As[(32 * wr + c16) * 40 + 8 * g]);
    bf16x8 a1 = *reinterpret_cast<const bf16x8*>(&As[(32 * wr + 16 + c16) * 40 + 8 * g]);
    bf16x8 b0 = *reinterpret_cast<const bf16x8*>(&Bs[(32 * wc + c16) * 40 + 8 * g]);
    bf16x8 b1 = *reinterpret_cast<const bf16x8*>(&Bs[(32 * wc + 16 + c16) * 40 + 8 * g]);
    acc[0][0] = mfma16(a0, b0, acc[0][0]);
    acc[0][1] = mfma16(a0, b1, acc[0][1]);
    acc[1][0] = mfma16(a1, b0, acc[1][0]);
    acc[1][1] = mfma16(a1, b1, acc[1][1]);
  }
#pragma unroll
  for (int i = 0; i < 2; ++i)
#pragma unroll
    for (int j = 0; j < 2; ++j)
#pragma unroll
      for (int e = 0; e < 4; ++e) {
        const int row = m0 + 32 * wr + 16 * i + 4 * g + e;
        const int col = n0 + 32 * wc + 16 * j + c16;
        const size_t idx = (size_t)row * 512 + col;
        out[idx] = acc[i][j][e] + xnf[idx];
      }
}

extern "C" void kernel_launch(void* const* d_in, const int* in_sizes, int n_in,
                              void* d_out, int out_size, void* d_ws, size_t ws_size,
                              hipStream_t stream) {
  const float* x = (const float*)d_in[0];
  const float* Wq = (const float*)d_in[1];
  const float* Wk = (const float*)d_in[2];
  const float* Wv = (const float*)d_in[3];
  const float* Wo = (const float*)d_in[4];
  const float* gamma = (const float*)d_in[5];
  const float* beta = (const float*)d_in[6];
  float* out = (float*)d_out;                    // [8192*512] fp32
  float* attn = out + (size_t)ROWS * DIM;        // [8*1024*8*1024] fp32

  char* ws = (char*)d_ws;
  float* xnf = (float*)ws;                                   // 16 MB
  short* xnb = (short*)(ws + (size_t)16 * 1024 * 1024);      // 8 MB
  short* WqT = (short*)(ws + (size_t)24 * 1024 * 1024);      // 0.5 MB
  short* WkT = WqT + 512 * 512;
  short* WvT = WkT + 512 * 512;
  short* WoT = WvT + 512 * 512;
  short* Qb = (short*)(ws + (size_t)26 * 1024 * 1024);       // 8 MB
  short* Kbp = (short*)(ws + (size_t)34 * 1024 * 1024);      // 8 MB
  short* Vt = (short*)(ws + (size_t)42 * 1024 * 1024);       // 8 MB
  short* Lg = (short*)(ws + (size_t)50 * 1024 * 1024);       // 8 MB (ends at 58 MB)

  ln_kernel<<<ROWS, 256, 0, stream>>>(x, gamma, beta, xnf, xnb);
  wtrans_kernel<<<dim3(1024, 4), 256, 0, stream>>>(Wq, Wk, Wv, Wo, WqT, WkT, WvT, WoT);
  gemm_qkv<<<dim3(128, 8, 3), 256, 0, stream>>>(xnb, WqT, WkT, WvT, Qb, Kbp, Vt);
  attn_kernel<<<dim3(64, NH, NB), 256, 0, stream>>>(Qb, Kbp, Vt, attn, Lg);
  gemm_out<<<dim3(128, 8), 256, 0, stream>>>(Lg, WoT, xnf, out);
}

// Round 2
// 193.848 us; speedup vs baseline: 1.0179x; 1.0179x over previous
//
#include <hip/hip_runtime.h>
#include <hip/hip_bf16.h>

typedef __attribute__((ext_vector_type(8))) short bf16x8;
typedef __attribute__((ext_vector_type(4))) short s16x4;
typedef __attribute__((ext_vector_type(4))) float f32x4;

#define DIM 512
#define NH 8
#define HD 64
#define SEQ 1024
#define NB 8
#define ROWS (NB*SEQ)

__device__ __forceinline__ short f2bf(float f) {
  union { float f; unsigned u; } v; v.f = f;
  unsigned r = v.u + 0x7fffu + ((v.u >> 16) & 1u);
  return (short)(r >> 16);
}

__device__ __forceinline__ f32x4 mfma16(bf16x8 a, bf16x8 b, f32x4 c) {
  return __builtin_amdgcn_mfma_f32_16x16x32_bf16(a, b, c, 0, 0, 0);
}

__device__ __forceinline__ void gload16(const void* g, void* l) {
  __builtin_amdgcn_global_load_lds(
      (const __attribute__((address_space(1))) unsigned int*)g,
      (__attribute__((address_space(3))) unsigned int*)l, 16, 0, 0);
}

// ---------------- LayerNorm: x[8192][512] -> xn fp32 + bf16 ----------------
__global__ __launch_bounds__(256) void ln_kernel(const float* __restrict__ x,
    const float* __restrict__ gamma, const float* __restrict__ beta,
    float* __restrict__ xnf, short* __restrict__ xnb) {
  const int row = blockIdx.x;
  const int t = threadIdx.x;
  const float2 v = reinterpret_cast<const float2*>(x + (size_t)row * DIM)[t];
  float s = v.x + v.y;
  float sq = v.x * v.x + v.y * v.y;
  for (int off = 1; off < 64; off <<= 1) {
    s += __shfl_xor(s, off);
    sq += __shfl_xor(sq, off);
  }
  __shared__ float sred[8];
  const int w = t >> 6, lane = t & 63;
  if (lane == 0) { sred[w] = s; sred[4 + w] = sq; }
  __syncthreads();
  s = sred[0] + sred[1] + sred[2] + sred[3];
  sq = sred[4] + sred[5] + sred[6] + sred[7];
  const float mean = s * (1.0f / DIM);
  const float var = sq * (1.0f / DIM) - mean * mean;
  const float rs = rsqrtf(var + 1e-5f);
  const float2 g = reinterpret_cast<const float2*>(gamma)[t];
  const float2 bb = reinterpret_cast<const float2*>(beta)[t];
  const float y0 = (v.x - mean) * rs * g.x + bb.x;
  const float y1 = (v.y - mean) * rs * g.y + bb.y;
  reinterpret_cast<float2*>(xnf + (size_t)row * DIM)[t] = make_float2(y0, y1);
  short2 o; o.x = f2bf(y0); o.y = f2bf(y1);
  reinterpret_cast<short2*>(xnb + (size_t)row * DIM)[t] = o;
}

// ------------- weights fp32 [k][n] -> bf16 [n][k]; qkv fused + Wo -------------
__global__ __launch_bounds__(256) void wtrans_kernel(
    const float* __restrict__ Wq, const float* __restrict__ Wk,
    const float* __restrict__ Wv, const float* __restrict__ Wo,
    short* __restrict__ WqkvT, short* __restrict__ WoT) {
  const int y = blockIdx.y;
  const int idx = blockIdx.x * 256 + threadIdx.x;  // 512*512 per weight
  const int n = idx >> 9, k = idx & 511;
  if (y < 3) {
    const float* W = (y == 0) ? Wq : (y == 1) ? Wk : Wv;
    WqkvT[((size_t)(y * 512 + n)) * 512 + k] = f2bf(W[(size_t)k * 512 + n]);
  } else {
    WoT[(size_t)n * 512 + k] = f2bf(Wo[(size_t)k * 512 + n]);
  }
}

// ---------------- m97-style 128x128 GEMM mainloop (BK=32) ----------------
// A row-major [M][512] bf16; BT row-major [N][512] bf16. XOR seg-swizzled LDS.
#define GEMM_MAIN(A_, BT_, m0_, n0_)                                          \
  f32x4 acc[4][4] = {};                                                       \
  {                                                                           \
    const int srow_a = w * 32 + (lane >> 2);                                  \
    const int key_a = (srow_a ^ (srow_a >> 2)) & 3;                           \
    const int sseg = (lane & 3) ^ key_a;                                      \
    const short* ga0 = A_ + (size_t)(m0_ + srow_a) * 512 + 8 * sseg;          \
    const short* ga1 = A_ + (size_t)(m0_ + srow_a + 16) * 512 + 8 * ((lane & 3) ^ (((srow_a + 16) ^ ((srow_a + 16) >> 2)) & 3)); \
    const short* gb0 = BT_ + (size_t)(n0_ + srow_a) * 512 + 8 * sseg;         \
    const short* gb1 = BT_ + (size_t)(n0_ + srow_a + 16) * 512 + 8 * ((lane & 3) ^ (((srow_a + 16) ^ ((srow_a + 16) >> 2)) & 3)); \
    for (int kb = 0; kb < 512; kb += 32) {                                    \
      __syncthreads();                                                        \
      gload16(ga0 + kb, &As[(w * 2 + 0) * 512]);                              \
      gload16(ga1 + kb, &As[(w * 2 + 1) * 512]);                              \
      gload16(gb0 + kb, &Bs[(w * 2 + 0) * 512]);                              \
      gload16(gb1 + kb, &Bs[(w * 2 + 1) * 512]);                              \
      __syncthreads();                                                        \
      bf16x8 af[4], bf[4];                                                    \
      _Pragma("unroll")                                                       \
      for (int i = 0; i < 4; ++i) {                                           \
        const int ra = 64 * wr + 16 * i + c16;                                \
        af[i] = *reinterpret_cast<const bf16x8*>(                             \
            &As[ra * 32 + 8 * (g ^ ((ra ^ (ra >> 2)) & 3))]);                 \
        const int rb = 64 * wc + 16 * i + c16;                                \
        bf[i] = *reinterpret_cast<const bf16x8*>(                             \
            &Bs[rb * 32 + 8 * (g ^ ((rb ^ (rb >> 2)) & 3))]);                 \
      }                                                                       \
      _Pragma("unroll")                                                       \
      for (int i = 0; i < 4; ++i)                                             \
        _Pragma("unroll")                                                     \
        for (int j = 0; j < 4; ++j)                                           \
          acc[i][j] = mfma16(af[i], bf[j], acc[i][j]);                        \
    }                                                                         \
  }

// QKV: xnb[8192][512] @ WqkvT -> Q,K row-major bf16; V transposed per (b,h)
__global__ __launch_bounds__(256) void gemm_qkv(const short* __restrict__ A,
    const short* __restrict__ BT, short* __restrict__ Qo,
    short* __restrict__ Ko, short* __restrict__ Vt) {
  __shared__ short As[128 * 32];
  __shared__ short Bs[128 * 32];
  const int m0 = blockIdx.x * 128, n0 = blockIdx.y * 128;
  const int t = threadIdx.x, w = t >> 6, lane = t & 63, g = lane >> 4, c16 = lane & 15;
  const int wr = w >> 1, wc = w & 1;
  GEMM_MAIN(A, BT, m0, n0)
  const int z = n0 >> 9;            // 0=Q 1=K 2=V
  const int nl = n0 & 511;
#pragma unroll
  for (int i = 0; i < 4; ++i)
#pragma unroll
    for (int j = 0; j < 4; ++j)
#pragma unroll
      for (int e = 0; e < 4; ++e) {
        const int row = m0 + 64 * wr + 16 * i + 4 * g + e;
        const int col = nl + 64 * wc + 16 * j + c16;
        const short v = f2bf(acc[i][j][e]);
        if (z == 0) {
          Qo[(size_t)row * 512 + col] = v;
        } else if (z == 1) {
          Ko[(size_t)row * 512 + col] = v;
        } else {
          const int bb = row >> 10, ss = row & 1023, hh = col >> 6, dd = col & 63;
          Vt[((size_t)(bb * NH + hh)) * 65536 + dd * 1024 + ss] = v;
        }
      }
}

// out = logits @ Wo + xn (fp32)
__global__ __launch_bounds__(256) void gemm_out(const short* __restrict__ A,
    const short* __restrict__ BT, const float* __restrict__ xnf,
    float* __restrict__ out) {
  __shared__ short As[128 * 32];
  __shared__ short Bs[128 * 32];
  const int m0 = blockIdx.x * 128, n0 = blockIdx.y * 128;
  const int t = threadIdx.x, w = t >> 6, lane = t & 63, g = lane >> 4, c16 = lane & 15;
  const int wr = w >> 1, wc = w & 1;
  GEMM_MAIN(A, BT, m0, n0)
#pragma unroll
  for (int i = 0; i < 4; ++i)
#pragma unroll
    for (int j = 0; j < 4; ++j)
#pragma unroll
      for (int e = 0; e < 4; ++e) {
        const int row = m0 + 64 * wr + 16 * i + 4 * g + e;
        const int col = n0 + 64 * wc + 16 * j + c16;
        const size_t idx = (size_t)row * 512 + col;
        out[idx] = acc[i][j][e] + xnf[idx];
      }
}

// ---------------- fused scores^T + softmax + attn write + PV ----------------
// grid (64, 8, 8), 256 thr, 16 Q-rows/block. S^T = mfma(K, Q): lane owns
// q = c16, k = c*128 + 32*w + 16*j + 4*g + e  -> coalesced float4 attn stores.
__global__ __launch_bounds__(256) void attn_kernel(
    const short* __restrict__ Qb, const short* __restrict__ Kb,
    const short* __restrict__ Vt, float* __restrict__ attnOut,
    short* __restrict__ Lg) {
  const int rb = blockIdx.x, h = blockIdx.y, b = blockIdx.z;
  const int inst = b * NH + h;
  const int t = threadIdx.x;
  const int w = t >> 6, lane = t & 63, g = lane >> 4, c16 = lane & 15;

  __shared__ short Klds[128 * 72];   // 128 K-rows x 64 d, pad 72
  __shared__ short Plds[16 * 1032];  // 16 q-rows x 1024 k, pad 1032
  __shared__ float red[2][4][16];

  bf16x8 qf0, qf1;
  {
    const short* qp = Qb + ((size_t)(b * SEQ + rb * 16 + c16)) * DIM + h * HD + 8 * g;
    qf0 = *reinterpret_cast<const bf16x8*>(qp);
    qf1 = *reinterpret_cast<const bf16x8*>(qp + 32);
  }

  // T14 split staging: prefetch chunk regs, write to LDS next iteration
  const int sr = t >> 3, sseg = t & 7;
  const short* kbase = Kb + ((size_t)(b * SEQ + sr)) * DIM + h * HD + 8 * sseg;
  bf16x8 kst[4];
#pragma unroll
  for (int p = 0; p < 4; ++p)
    kst[p] = *reinterpret_cast<const bf16x8*>(kbase + (size_t)(p * 32) * DIM);

  f32x4 acc[16] = {};

  for (int c = 0; c < 8; ++c) {
    __syncthreads();
#pragma unroll
    for (int p = 0; p < 4; ++p)
      *reinterpret_cast<bf16x8*>(&Klds[(p * 32 + sr) * 72 + 8 * sseg]) = kst[p];
    if (c < 7) {
#pragma unroll
      for (int p = 0; p < 4; ++p)
        kst[p] = *reinterpret_cast<const bf16x8*>(
            kbase + (size_t)((c + 1) * 128 + p * 32) * DIM);
    }
    __syncthreads();
#pragma unroll
    for (int j = 0; j < 2; ++j) {
      const int lr = 32 * w + 16 * j + c16;
      bf16x8 k0 = *reinterpret_cast<const bf16x8*>(&Klds[lr * 72 + 8 * g]);
      bf16x8 k1 = *reinterpret_cast<const bf16x8*>(&Klds[lr * 72 + 32 + 8 * g]);
      const int tt = c * 2 + j;
      acc[tt] = mfma16(k0, qf0, acc[tt]);   // S^T: A=K rows, B=Q rows
      acc[tt] = mfma16(k1, qf1, acc[tt]);
    }
  }

  // softmax over k for fixed q=c16: in-lane then lanes +-16,+-32 then waves
  float m = -1e30f;
#pragma unroll
  for (int tt = 0; tt < 16; ++tt)
#pragma unroll
    for (int e = 0; e < 4; ++e) {
      acc[tt][e] *= 0.125f;
      m = fmaxf(m, acc[tt][e]);
    }
  m = fmaxf(m, __shfl_xor(m, 16));
  m = fmaxf(m, __shfl_xor(m, 32));
  if (g == 0) red[0][w][c16] = m;
  __syncthreads();
  m = fmaxf(fmaxf(red[0][0][c16], red[0][1][c16]),
            fmaxf(red[0][2][c16], red[0][3][c16]));

  float sm = 0.f;
#pragma unroll
  for (int tt = 0; tt < 16; ++tt)
#pragma unroll
    for (int e = 0; e < 4; ++e) {
      const float p = __expf(acc[tt][e] - m);
      acc[tt][e] = p;
      sm += p;
    }
  sm += __shfl_xor(sm, 16);
  sm += __shfl_xor(sm, 32);
  if (g == 0) red[1][w][c16] = sm;
  __syncthreads();
  const float rinv = 1.0f / (red[1][0][c16] + red[1][1][c16] +
                             red[1][2][c16] + red[1][3][c16]);

  // write attn fp32 (dwordx4) + stage P bf16 (ds_write_b64)
  float* arow = attnOut + (size_t)b * 8388608 +
                (size_t)(rb * 16 + c16) * 8192 + h * 1024;
#pragma unroll
  for (int c = 0; c < 8; ++c)
#pragma unroll
    for (int j = 0; j < 2; ++j) {
      const int tt = c * 2 + j;
      const int k0 = c * 128 + 32 * w + 16 * j + 4 * g;
      f32x4 pv;
#pragma unroll
      for (int e = 0; e < 4; ++e) pv[e] = acc[tt][e] * rinv;
      *reinterpret_cast<f32x4*>(arow + k0) = pv;
      s16x4 pb;
#pragma unroll
      for (int e = 0; e < 4; ++e) pb[e] = f2bf(pv[e]);
      *reinterpret_cast<s16x4*>(&Plds[c16 * 1032 + k0]) = pb;
    }
  __syncthreads();

  // PV: logits[16 x 64] = P[16 x 1024] @ V[1024 x 64]; wave w -> d in [16w,16w+16)
  f32x4 pacc = {};
  const short* vbase = Vt + (size_t)inst * 65536 + (16 * w + c16) * 1024 + 8 * g;
#pragma unroll
  for (int kk = 0; kk < 32; ++kk) {
    bf16x8 pa = *reinterpret_cast<const bf16x8*>(&Plds[c16 * 1032 + 32 * kk + 8 * g]);
    bf16x8 vb = *reinterpret_cast<const bf16x8*>(vbase + 32 * kk);
    pacc = mfma16(pa, vb, pacc);
  }
#pragma unroll
  for (int e = 0; e < 4; ++e) {
    Lg[((size_t)(b * SEQ + rb * 16 + 4 * g + e)) * DIM + h * HD + 16 * w + c16] =
        f2bf(pacc[e]);
  }
}

extern "C" void kernel_launch(void* const* d_in, const int* in_sizes, int n_in,
                              void* d_out, int out_size, void* d_ws, size_t ws_size,
                              hipStream_t stream) {
  const float* x = (const float*)d_in[0];
  const float* Wq = (const float*)d_in[1];
  const float* Wk = (const float*)d_in[2];
  const float* Wv = (const float*)d_in[3];
  const float* Wo = (const float*)d_in[4];
  const float* gamma = (const float*)d_in[5];
  const float* beta = (const float*)d_in[6];
  float* out = (float*)d_out;                    // [8192*512] fp32
  float* attn = out + (size_t)ROWS * DIM;        // [8*1024*8*1024] fp32

  char* ws = (char*)d_ws;
  float* xnf = (float*)ws;                                   // 16 MB
  short* xnb = (short*)(ws + (size_t)16 * 1024 * 1024);      // 8 MB
  short* WqkvT = (short*)(ws + (size_t)24 * 1024 * 1024);    // 1.5 MB
  short* WoT = WqkvT + 1536 * 512;                           // 0.5 MB
  short* Qb = (short*)(ws + (size_t)26 * 1024 * 1024);       // 8 MB
  short* Kbp = (short*)(ws + (size_t)34 * 1024 * 1024);      // 8 MB
  short* Vt = (short*)(ws + (size_t)42 * 1024 * 1024);       // 8 MB
  short* Lg = (short*)(ws + (size_t)50 * 1024 * 1024);       // 8 MB (ends 58 MB)

  ln_kernel<<<ROWS, 256, 0, stream>>>(x, gamma, beta, xnf, xnb);
  wtrans_kernel<<<dim3(1024, 4), 256, 0, stream>>>(Wq, Wk, Wv, Wo, WqkvT, WoT);
  gemm_qkv<<<dim3(64, 12), 256, 0, stream>>>(xnb, WqkvT, Qb, Kbp, Vt);
  attn_kernel<<<dim3(64, NH, NB), 256, 0, stream>>>(Qb, Kbp, Vt, attn, Lg);
  gemm_out<<<dim3(64, 4), 256, 0, stream>>>(Lg, WoT, xnf, out);
}